// Round 1
// 1559.072 us; speedup vs baseline: 1.2607x; 1.2607x over previous
//
#include <hip/hip_runtime.h>
#include <hip/hip_bf16.h>

#define NDIM 100
#define HDIM 16
#define CDIM 20

#define BSHIFT 8                 // 256 nodes per bucket
#define BMASK  ((1 << BSHIFT) - 1)
#define NBMAX  2048              // max buckets (N <= 2048*256 = 524288)
#define PPART  8                 // partitions ~ XCDs (blockIdx & 7)
#define CHUNK  8192              // edges per block in passes A/B

// ---------------- pass A: per-chunk bucket histogram -> hist[p][b] ----------------

__global__ __launch_bounds__(256) void histA(const int* __restrict__ dst,
                                             int* __restrict__ hist,
                                             int E, int NB) {
    __shared__ int lh[NBMAX];
    for (int t = threadIdx.x; t < NB; t += 256) lh[t] = 0;
    __syncthreads();

    int p = blockIdx.x & (PPART - 1);
    int base = blockIdx.x * CHUNK;
    int endv = min(base + CHUNK, E);
    for (int e = base + threadIdx.x; e < endv; e += 256)
        atomicAdd(&lh[dst[e] >> BSHIFT], 1);
    __syncthreads();

    int* hp = hist + p * NB;
    for (int t = threadIdx.x; t < NB; t += 256) {
        int v = lh[t];
        if (v) atomicAdd(&hp[t], v);
    }
}

// ---------------- bucket totals: bcnt[b] = sum_p hist[p][b] ----------------

__global__ __launch_bounds__(256) void bucket_tot(const int* __restrict__ hist,
                                                  int* __restrict__ bcnt, int NB) {
    int b = blockIdx.x * 256 + threadIdx.x;
    if (b < NB) {
        int s = 0;
#pragma unroll
        for (int p = 0; p < PPART; ++p) s += hist[p * NB + b];
        bcnt[b] = s;
    }
}

// ---------------- exclusive scan of bcnt in place (nb <= 2048), 1 block ----------------

__global__ __launch_bounds__(256) void scan_k2(int* __restrict__ bsum, int nb) {
    __shared__ int part[256];
    int t = threadIdx.x;
    int base = t * 8;
    int loc[8];
    int s = 0;
#pragma unroll
    for (int k = 0; k < 8; ++k) {
        int idx = base + k;
        loc[k] = (idx < nb) ? bsum[idx] : 0;
        s += loc[k];
    }
    part[t] = s;
    __syncthreads();
    for (int off = 1; off < 256; off <<= 1) {
        int add = (t >= off) ? part[t - off] : 0;
        __syncthreads();
        part[t] += add;
        __syncthreads();
    }
    int run = (t > 0) ? part[t - 1] : 0;
#pragma unroll
    for (int k = 0; k < 8; ++k) {
        int idx = base + k;
        if (idx < nb) bsum[idx] = run;
        run += loc[k];
    }
}

// ---------------- per-(partition,bucket) start cursors ----------------

__global__ __launch_bounds__(256) void part_offsets(const int* __restrict__ hist,
                                                    const int* __restrict__ B0,
                                                    int* __restrict__ gcur, int NB) {
    int b = blockIdx.x * 256 + threadIdx.x;
    if (b < NB) {
        int run = B0[b];
#pragma unroll
        for (int p = 0; p < PPART; ++p) {
            gcur[p * NB + b] = run;
            run += hist[p * NB + b];
        }
    }
}

// ---------------- pass B: scatter packed (src<<8 | dst&255) into bucket-major tmp ----------------
// Same chunking / partition mapping as pass A, so (p,b) capacities match exactly.

__global__ __launch_bounds__(256) void scatterB(const int* __restrict__ src,
                                                const int* __restrict__ dst,
                                                int* __restrict__ gcur,
                                                unsigned* __restrict__ tmp,
                                                int E, int NB) {
    int p = blockIdx.x & (PPART - 1);
    int* gp = gcur + p * NB;
    int base = blockIdx.x * CHUNK;
    int endv = min(base + CHUNK, E);
    for (int e = base + threadIdx.x; e < endv; e += 256) {
        int d = dst[e];
        int b = d >> BSHIFT;
        int pos = atomicAdd(&gp[b], 1);
        tmp[pos] = ((unsigned)src[e] << BSHIFT) | (unsigned)(d & BMASK);
    }
}

// ---------------- pass C: one block per bucket -> deg, cursor(end), esrc ----------------
// Writes confined to the bucket's contiguous ~16KB esrc window; LDS atomics.

__global__ __launch_bounds__(256) void binC(const unsigned* __restrict__ tmp,
                                            const int* __restrict__ B0,
                                            int* __restrict__ deg,
                                            int* __restrict__ cursor,
                                            int* __restrict__ esrc,
                                            int N, int E, int NB) {
    __shared__ int lh[256];
    __shared__ int lcur[256];
    int b = blockIdx.x;
    int t = threadIdx.x;
    lh[t] = 0;
    __syncthreads();

    int lo = B0[b];
    int hi = (b + 1 < NB) ? B0[b + 1] : E;

    // sweep 1: per-node histogram (= in-degree)
    for (int i = lo + t; i < hi; i += 256)
        atomicAdd(&lh[tmp[i] & BMASK], 1);
    __syncthreads();

    int cnt = lh[t];
    __syncthreads();
    // inclusive scan of lh
    for (int off = 1; off < 256; off <<= 1) {
        int add = (t >= off) ? lh[t - off] : 0;
        __syncthreads();
        lh[t] += add;
        __syncthreads();
    }
    int end   = lo + lh[t];
    int start = end - cnt;

    int node = (b << BSHIFT) + t;
    if (node < N) {
        deg[node]    = cnt;   // in-degree (self-loop handled analytically)
        cursor[node] = end;   // segment end, as gather kernels expect
    }
    lcur[t] = start;
    __syncthreads();

    // sweep 2: scatter into the bucket's esrc window
    for (int i = lo + t; i < hi; i += 256) {
        unsigned v = tmp[i];
        int pos = atomicAdd(&lcur[v & BMASK], 1);
        esrc[pos] = (int)(v >> BSHIFT);
    }
}

// ---------------- dinv ----------------

__global__ __launch_bounds__(256) void dinv_kernel(const int* __restrict__ deg,
                                                   float* __restrict__ dinv, int N) {
    int i = blockIdx.x * blockDim.x + threadIdx.x;
    if (i < N) dinv[i] = rsqrtf((float)(deg[i] + 1));  // +1 = self-loop
}

// ---------------- xw1 = x @ W1  ([N,100] @ [100,16]) ----------------

__global__ __launch_bounds__(256) void xw1_kernel(const float* __restrict__ x,
                                                  const float* __restrict__ W1,
                                                  float* __restrict__ xw1, int N) {
    __shared__ float Ws[NDIM * HDIM];  // [k][j]
    for (int t = threadIdx.x; t < NDIM * HDIM; t += 256) Ws[t] = W1[t];
    __syncthreads();

    const int ln = threadIdx.x >> 2;
    const int q  = threadIdx.x & 3;
    const int node = blockIdx.x * 64 + ln;
    if (node >= N) return;

    const float4* xr  = reinterpret_cast<const float4*>(x + (size_t)node * NDIM);
    const float4* Ws4 = reinterpret_cast<const float4*>(Ws);

    float4 acc = make_float4(0.f, 0.f, 0.f, 0.f);
#pragma unroll
    for (int kk = 0; kk < NDIM / 4; ++kk) {
        float4 xv = xr[kk];
        float xs[4] = {xv.x, xv.y, xv.z, xv.w};
#pragma unroll
        for (int c = 0; c < 4; ++c) {
            float4 w = Ws4[(kk * 4 + c) * 4 + q];
            acc.x += xs[c] * w.x;
            acc.y += xs[c] * w.y;
            acc.z += xs[c] * w.z;
            acc.w += xs[c] * w.w;
        }
    }
    reinterpret_cast<float4*>(xw1 + (size_t)node * HDIM)[q] = acc;
}

// ---------------- layer-1 gather-reduce + epilogue: h = relu(...) ----------------

__global__ __launch_bounds__(256) void gather1(const int* __restrict__ esrc,
                                               const int* __restrict__ cursor,
                                               const int* __restrict__ deg,
                                               const float* __restrict__ dinv,
                                               const float* __restrict__ xw1,
                                               const float* __restrict__ b1,
                                               float* __restrict__ h, int N) {
    int g = threadIdx.x >> 4;
    int f = threadIdx.x & 15;
    int n = blockIdx.x * 16 + g;
    if (n >= N) return;

    int end = cursor[n];
    int len = deg[n];
    int start = end - len;
    float dn = dinv[n];

    float acc = 0.f;
    for (int j = start; j < end; ++j) {
        int s = esrc[j];
        acc += dinv[s] * xw1[(size_t)s * HDIM + f];
    }
    float v = dn * acc + dn * dn * xw1[(size_t)n * HDIM + f] + b1[f];
    h[(size_t)n * HDIM + f] = fmaxf(v, 0.f);
}

// ---------------- xw2 = h @ W2  ([N,16] @ [16,20]) ----------------

__global__ __launch_bounds__(256) void xw2_kernel(const float* __restrict__ h,
                                                  const float* __restrict__ W2,
                                                  float* __restrict__ xw2, int N) {
    __shared__ float W2t[CDIM * HDIM];  // [j][k]
    for (int t = threadIdx.x; t < CDIM * HDIM; t += 256) {
        int j = t / HDIM, k = t % HDIM;
        W2t[t] = W2[k * CDIM + j];
    }
    __syncthreads();

    int n = blockIdx.x * blockDim.x + threadIdx.x;
    if (n >= N) return;

    float hv[HDIM];
    const float4* h4 = reinterpret_cast<const float4*>(h + (size_t)n * HDIM);
#pragma unroll
    for (int c = 0; c < HDIM / 4; ++c) {
        float4 a = h4[c];
        hv[4 * c + 0] = a.x; hv[4 * c + 1] = a.y;
        hv[4 * c + 2] = a.z; hv[4 * c + 3] = a.w;
    }
    float o[CDIM];
#pragma unroll
    for (int j = 0; j < CDIM; ++j) {
        const float4* w4 = reinterpret_cast<const float4*>(W2t + j * HDIM);
        float s = 0.f;
#pragma unroll
        for (int c = 0; c < HDIM / 4; ++c) {
            float4 w = w4[c];
            s += hv[4 * c + 0] * w.x + hv[4 * c + 1] * w.y +
                 hv[4 * c + 2] * w.z + hv[4 * c + 3] * w.w;
        }
        o[j] = s;
    }
    float4* out4 = reinterpret_cast<float4*>(xw2 + (size_t)n * CDIM);
#pragma unroll
    for (int c = 0; c < CDIM / 4; ++c)
        out4[c] = make_float4(o[4 * c], o[4 * c + 1], o[4 * c + 2], o[4 * c + 3]);
}

// ---------------- layer-2 gather-reduce: logits -> d_out ----------------

__global__ __launch_bounds__(256) void gather2(const int* __restrict__ esrc,
                                               const int* __restrict__ cursor,
                                               const int* __restrict__ deg,
                                               const float* __restrict__ dinv,
                                               const float* __restrict__ xw2,
                                               const float* __restrict__ b2,
                                               float* __restrict__ logits, int N) {
    int g = threadIdx.x >> 5;
    int f = threadIdx.x & 31;
    int n = blockIdx.x * 8 + g;
    if (n >= N) return;

    int end = cursor[n];
    int len = deg[n];
    int start = end - len;
    float dn = dinv[n];

    float acc = 0.f;
    for (int j = start; j < end; ++j) {
        int s = esrc[j];
        float ds = dinv[s];
        if (f < CDIM) acc += ds * xw2[(size_t)s * CDIM + f];
    }
    if (f < CDIM) {
        float t = dn * acc + dn * dn * xw2[(size_t)n * CDIM + f] + b2[f];
        logits[(size_t)n * CDIM + f] = t;
    }
}

// ---------------- in-place log_softmax over d_out rows ----------------

__global__ __launch_bounds__(256) void logsoftmax_kernel(float* __restrict__ out, int N) {
    int n = blockIdx.x * blockDim.x + threadIdx.x;
    if (n >= N) return;
    float t[CDIM];
    float4* o4 = reinterpret_cast<float4*>(out + (size_t)n * CDIM);
#pragma unroll
    for (int c = 0; c < CDIM / 4; ++c) {
        float4 a = o4[c];
        t[4 * c + 0] = a.x; t[4 * c + 1] = a.y;
        t[4 * c + 2] = a.z; t[4 * c + 3] = a.w;
    }
    float m = t[0];
#pragma unroll
    for (int j = 1; j < CDIM; ++j) m = fmaxf(m, t[j]);
    float s = 0.f;
#pragma unroll
    for (int j = 0; j < CDIM; ++j) s += __expf(t[j] - m);
    float l = __logf(s);
#pragma unroll
    for (int c = 0; c < CDIM / 4; ++c)
        o4[c] = make_float4(t[4 * c + 0] - m - l, t[4 * c + 1] - m - l,
                            t[4 * c + 2] - m - l, t[4 * c + 3] - m - l);
}

// ---------------- launch ----------------

extern "C" void kernel_launch(void* const* d_in, const int* in_sizes, int n_in,
                              void* d_out, int out_size, void* d_ws, size_t ws_size,
                              hipStream_t stream) {
    const float* x  = (const float*)d_in[0];
    const int* edge = (const int*)d_in[1];   // [2, E] int32
    const float* W1 = (const float*)d_in[2];
    const float* b1 = (const float*)d_in[3];
    const float* W2 = (const float*)d_in[4];
    const float* b2 = (const float*)d_in[5];
    float* out = (float*)d_out;

    const int N = in_sizes[0] / NDIM;   // 500000
    const int E = in_sizes[1] / 2;      // 8000000
    const int* src = edge;
    const int* dst = edge + E;

    const int tb = 256;
    const int nbN = (N + tb - 1) / tb;          // blocks over N
    const int NB  = (N + BMASK) >> BSHIFT;      // buckets (1954), <= NBMAX
    const int nbE = (E + CHUNK - 1) / CHUNK;    // chunks for passes A/B

    char* ws = (char*)d_ws;
    size_t off = 0;
    int*   deg    = (int*)(ws + off);   off += (size_t)N * 4;
    int*   cursor = (int*)(ws + off);   off += (size_t)N * 4;
    float* dinv   = (float*)(ws + off); off += (size_t)N * 4;
    float* xw1    = (float*)(ws + off); off += (size_t)N * HDIM * 4;
    float* h      = (float*)(ws + off); off += (size_t)N * HDIM * 4;
    float* xw2    = (float*)(ws + off); off += (size_t)N * CDIM * 4;
    int*   esrc   = (int*)(ws + off);   off += (size_t)E * 4;
    int*   hist   = (int*)(ws + off);   off += (size_t)PPART * NBMAX * 4;
    int*   gcur   = (int*)(ws + off);   off += (size_t)PPART * NBMAX * 4;
    int*   bcnt   = (int*)(ws + off);   off += (size_t)NBMAX * 4;

    // tmp (bucket-major packed edges, E*4 bytes) aliases xw2 (N*CDIM*4 = 40MB >= 32MB);
    // xw2 is only written after binC has consumed tmp.
    unsigned* tmp = (unsigned*)xw2;

    // ---- CSR build via hierarchical counting sort ----
    hipMemsetAsync(hist, 0, (size_t)PPART * NB * 4, stream);
    histA<<<nbE, tb, 0, stream>>>(dst, hist, E, NB);
    bucket_tot<<<(NB + tb - 1) / tb, tb, 0, stream>>>(hist, bcnt, NB);
    scan_k2<<<1, tb, 0, stream>>>(bcnt, NB);                        // bcnt -> B0 (exclusive)
    part_offsets<<<(NB + tb - 1) / tb, tb, 0, stream>>>(hist, bcnt, gcur, NB);
    scatterB<<<nbE, tb, 0, stream>>>(src, dst, gcur, tmp, E, NB);
    binC<<<NB, tb, 0, stream>>>(tmp, bcnt, deg, cursor, esrc, N, E, NB);

    dinv_kernel<<<nbN, tb, 0, stream>>>(deg, dinv, N);

    // dense matmul xw1
    xw1_kernel<<<(N + 63) / 64, tb, 0, stream>>>(x, W1, xw1, N);

    // layer 1: gather-reduce + relu epilogue
    gather1<<<(N + 15) / 16, tb, 0, stream>>>(esrc, cursor, deg, dinv, xw1, b1, h, N);

    // dense matmul xw2
    xw2_kernel<<<nbN, tb, 0, stream>>>(h, W2, xw2, N);

    // layer 2: gather-reduce -> logits in d_out
    gather2<<<(N + 7) / 8, tb, 0, stream>>>(esrc, cursor, deg, dinv, xw2, b2, out, N);

    // in-place log_softmax
    logsoftmax_kernel<<<nbN, tb, 0, stream>>>(out, N);
}

// Round 2
// 1027.043 us; speedup vs baseline: 1.9138x; 1.5180x over previous
//
#include <hip/hip_runtime.h>
#include <hip/hip_bf16.h>

#define NDIM 100
#define HDIM 16
#define CDIM 20

#define BSHIFT 8                 // 256 nodes per bucket
#define BMASK  ((1 << BSHIFT) - 1)
#define NBMAX  2048              // max buckets (N <= 2048*256 = 524288)
#define PPART  8                 // partitions ~ XCDs (blockIdx & 7)
#define CHUNK  8192              // edges per block in passes A/B

// ---------------- pass A: per-chunk bucket histogram -> hist[p][b] ----------------

__global__ __launch_bounds__(256) void histA(const int* __restrict__ dst,
                                             int* __restrict__ hist,
                                             int E, int NB) {
    __shared__ int lh[NBMAX];
    for (int t = threadIdx.x; t < NB; t += 256) lh[t] = 0;
    __syncthreads();

    int p = blockIdx.x & (PPART - 1);
    int base = blockIdx.x * CHUNK;
    int endv = min(base + CHUNK, E);
    for (int e = base + threadIdx.x; e < endv; e += 256)
        atomicAdd(&lh[dst[e] >> BSHIFT], 1);
    __syncthreads();

    int* hp = hist + p * NB;
    for (int t = threadIdx.x; t < NB; t += 256) {
        int v = lh[t];
        if (v) atomicAdd(&hp[t], v);
    }
}

// ---------------- bucket totals: bcnt[b] = sum_p hist[p][b] ----------------

__global__ __launch_bounds__(256) void bucket_tot(const int* __restrict__ hist,
                                                  int* __restrict__ bcnt, int NB) {
    int b = blockIdx.x * 256 + threadIdx.x;
    if (b < NB) {
        int s = 0;
#pragma unroll
        for (int p = 0; p < PPART; ++p) s += hist[p * NB + b];
        bcnt[b] = s;
    }
}

// ---------------- exclusive scan of bcnt in place (nb <= 2048), 1 block ----------------

__global__ __launch_bounds__(256) void scan_k2(int* __restrict__ bsum, int nb) {
    __shared__ int part[256];
    int t = threadIdx.x;
    int base = t * 8;
    int loc[8];
    int s = 0;
#pragma unroll
    for (int k = 0; k < 8; ++k) {
        int idx = base + k;
        loc[k] = (idx < nb) ? bsum[idx] : 0;
        s += loc[k];
    }
    part[t] = s;
    __syncthreads();
    for (int off = 1; off < 256; off <<= 1) {
        int add = (t >= off) ? part[t - off] : 0;
        __syncthreads();
        part[t] += add;
        __syncthreads();
    }
    int run = (t > 0) ? part[t - 1] : 0;
#pragma unroll
    for (int k = 0; k < 8; ++k) {
        int idx = base + k;
        if (idx < nb) bsum[idx] = run;
        run += loc[k];
    }
}

// ---------------- per-(partition,bucket) start cursors ----------------

__global__ __launch_bounds__(256) void part_offsets(const int* __restrict__ hist,
                                                    const int* __restrict__ B0,
                                                    int* __restrict__ gcur, int NB) {
    int b = blockIdx.x * 256 + threadIdx.x;
    if (b < NB) {
        int run = B0[b];
#pragma unroll
        for (int p = 0; p < PPART; ++p) {
            gcur[p * NB + b] = run;
            run += hist[p * NB + b];
        }
    }
}

// ---------------- pass B: scatter packed (src<<8 | dst&255) into bucket-major tmp ----------------

__global__ __launch_bounds__(256) void scatterB(const int* __restrict__ src,
                                                const int* __restrict__ dst,
                                                int* __restrict__ gcur,
                                                unsigned* __restrict__ tmp,
                                                int E, int NB) {
    int p = blockIdx.x & (PPART - 1);
    int* gp = gcur + p * NB;
    int base = blockIdx.x * CHUNK;
    int endv = min(base + CHUNK, E);
    for (int e = base + threadIdx.x; e < endv; e += 256) {
        int d = dst[e];
        int b = d >> BSHIFT;
        int pos = atomicAdd(&gp[b], 1);
        tmp[pos] = ((unsigned)src[e] << BSHIFT) | (unsigned)(d & BMASK);
    }
}

// ---------------- pass C: one block per bucket -> deg, cursor(end), esrc ----------------

__global__ __launch_bounds__(256) void binC(const unsigned* __restrict__ tmp,
                                            const int* __restrict__ B0,
                                            int* __restrict__ deg,
                                            int* __restrict__ cursor,
                                            int* __restrict__ esrc,
                                            int N, int E, int NB) {
    __shared__ int lh[256];
    __shared__ int lcur[256];
    int b = blockIdx.x;
    int t = threadIdx.x;
    lh[t] = 0;
    __syncthreads();

    int lo = B0[b];
    int hi = (b + 1 < NB) ? B0[b + 1] : E;

    for (int i = lo + t; i < hi; i += 256)
        atomicAdd(&lh[tmp[i] & BMASK], 1);
    __syncthreads();

    int cnt = lh[t];
    __syncthreads();
    for (int off = 1; off < 256; off <<= 1) {
        int add = (t >= off) ? lh[t - off] : 0;
        __syncthreads();
        lh[t] += add;
        __syncthreads();
    }
    int end   = lo + lh[t];
    int start = end - cnt;

    int node = (b << BSHIFT) + t;
    if (node < N) {
        deg[node]    = cnt;
        cursor[node] = end;
    }
    lcur[t] = start;
    __syncthreads();

    for (int i = lo + t; i < hi; i += 256) {
        unsigned v = tmp[i];
        int pos = atomicAdd(&lcur[v & BMASK], 1);
        esrc[pos] = (int)(v >> BSHIFT);
    }
}

// ---------------- dinv ----------------

__global__ __launch_bounds__(256) void dinv_kernel(const int* __restrict__ deg,
                                                   float* __restrict__ dinv, int N) {
    int i = blockIdx.x * blockDim.x + threadIdx.x;
    if (i < N) dinv[i] = rsqrtf((float)(deg[i] + 1));  // +1 = self-loop
}

// ---------------- xw1s = dinv[n] * (x @ W1)  ([N,100] @ [100,16], pre-scaled) ----------------

__global__ __launch_bounds__(256) void xw1_kernel(const float* __restrict__ x,
                                                  const float* __restrict__ W1,
                                                  const float* __restrict__ dinv,
                                                  float* __restrict__ xw1s, int N) {
    __shared__ float Ws[NDIM * HDIM];  // [k][j]
    for (int t = threadIdx.x; t < NDIM * HDIM; t += 256) Ws[t] = W1[t];
    __syncthreads();

    const int ln = threadIdx.x >> 2;
    const int q  = threadIdx.x & 3;
    const int node = blockIdx.x * 64 + ln;
    if (node >= N) return;

    const float4* xr  = reinterpret_cast<const float4*>(x + (size_t)node * NDIM);
    const float4* Ws4 = reinterpret_cast<const float4*>(Ws);

    float4 acc = make_float4(0.f, 0.f, 0.f, 0.f);
#pragma unroll
    for (int kk = 0; kk < NDIM / 4; ++kk) {
        float4 xv = xr[kk];
        float xs[4] = {xv.x, xv.y, xv.z, xv.w};
#pragma unroll
        for (int c = 0; c < 4; ++c) {
            float4 w = Ws4[(kk * 4 + c) * 4 + q];
            acc.x += xs[c] * w.x;
            acc.y += xs[c] * w.y;
            acc.z += xs[c] * w.z;
            acc.w += xs[c] * w.w;
        }
    }
    float dn = dinv[node];
    acc.x *= dn; acc.y *= dn; acc.z *= dn; acc.w *= dn;
    reinterpret_cast<float4*>(xw1s + (size_t)node * HDIM)[q] = acc;
}

// ---------------- layer-1 gather: hs = dinv * relu(dn*(sum xw1s[s] + xw1s[n]) + b1) ----
// 4 lanes per node, float4 per lane; 64 nodes per 256-thread block.

__global__ __launch_bounds__(256) void gather1(const int* __restrict__ esrc,
                                               const int* __restrict__ cursor,
                                               const int* __restrict__ deg,
                                               const float* __restrict__ dinv,
                                               const float* __restrict__ xw1s,
                                               const float* __restrict__ b1,
                                               float* __restrict__ hs, int N) {
    int g  = threadIdx.x >> 2;
    int f4 = threadIdx.x & 3;
    int n  = blockIdx.x * 64 + g;
    if (n >= N) return;

    int end   = cursor[n];
    int start = end - deg[n];
    float dn  = dinv[n];

    const float4* T = reinterpret_cast<const float4*>(xw1s);
    float4 a0 = T[(size_t)n * 4 + f4];  // self term (already dinv-scaled)
    float4 a1 = make_float4(0.f, 0.f, 0.f, 0.f);

    int j = start;
    for (; j + 3 < end; j += 4) {
        int s0 = esrc[j + 0], s1 = esrc[j + 1];
        int s2 = esrc[j + 2], s3 = esrc[j + 3];
        float4 v0 = T[(size_t)s0 * 4 + f4];
        float4 v1 = T[(size_t)s1 * 4 + f4];
        float4 v2 = T[(size_t)s2 * 4 + f4];
        float4 v3 = T[(size_t)s3 * 4 + f4];
        a0.x += v0.x; a0.y += v0.y; a0.z += v0.z; a0.w += v0.w;
        a1.x += v1.x; a1.y += v1.y; a1.z += v1.z; a1.w += v1.w;
        a0.x += v2.x; a0.y += v2.y; a0.z += v2.z; a0.w += v2.w;
        a1.x += v3.x; a1.y += v3.y; a1.z += v3.z; a1.w += v3.w;
    }
    for (; j < end; ++j) {
        int s = esrc[j];
        float4 v = T[(size_t)s * 4 + f4];
        a0.x += v.x; a0.y += v.y; a0.z += v.z; a0.w += v.w;
    }
    float4 acc = make_float4(a0.x + a1.x, a0.y + a1.y, a0.z + a1.z, a0.w + a1.w);
    float4 bv = reinterpret_cast<const float4*>(b1)[f4];
    float4 hv;
    hv.x = dn * fmaxf(dn * acc.x + bv.x, 0.f);
    hv.y = dn * fmaxf(dn * acc.y + bv.y, 0.f);
    hv.z = dn * fmaxf(dn * acc.z + bv.z, 0.f);
    hv.w = dn * fmaxf(dn * acc.w + bv.w, 0.f);
    reinterpret_cast<float4*>(hs)[(size_t)n * 4 + f4] = hv;
}

// ---------------- layer-2 gather: agg2 = dn * (sum hs[s] + hs[n]) ----------------

__global__ __launch_bounds__(256) void gather2(const int* __restrict__ esrc,
                                               const int* __restrict__ cursor,
                                               const int* __restrict__ deg,
                                               const float* __restrict__ dinv,
                                               const float* __restrict__ hs,
                                               float* __restrict__ agg2, int N) {
    int g  = threadIdx.x >> 2;
    int f4 = threadIdx.x & 3;
    int n  = blockIdx.x * 64 + g;
    if (n >= N) return;

    int end   = cursor[n];
    int start = end - deg[n];
    float dn  = dinv[n];

    const float4* T = reinterpret_cast<const float4*>(hs);
    float4 a0 = T[(size_t)n * 4 + f4];  // self term
    float4 a1 = make_float4(0.f, 0.f, 0.f, 0.f);

    int j = start;
    for (; j + 3 < end; j += 4) {
        int s0 = esrc[j + 0], s1 = esrc[j + 1];
        int s2 = esrc[j + 2], s3 = esrc[j + 3];
        float4 v0 = T[(size_t)s0 * 4 + f4];
        float4 v1 = T[(size_t)s1 * 4 + f4];
        float4 v2 = T[(size_t)s2 * 4 + f4];
        float4 v3 = T[(size_t)s3 * 4 + f4];
        a0.x += v0.x; a0.y += v0.y; a0.z += v0.z; a0.w += v0.w;
        a1.x += v1.x; a1.y += v1.y; a1.z += v1.z; a1.w += v1.w;
        a0.x += v2.x; a0.y += v2.y; a0.z += v2.z; a0.w += v2.w;
        a1.x += v3.x; a1.y += v3.y; a1.z += v3.z; a1.w += v3.w;
    }
    for (; j < end; ++j) {
        int s = esrc[j];
        float4 v = T[(size_t)s * 4 + f4];
        a0.x += v.x; a0.y += v.y; a0.z += v.z; a0.w += v.w;
    }
    float4 o;
    o.x = dn * (a0.x + a1.x);
    o.y = dn * (a0.y + a1.y);
    o.z = dn * (a0.z + a1.z);
    o.w = dn * (a0.w + a1.w);
    reinterpret_cast<float4*>(agg2)[(size_t)n * 4 + f4] = o;
}

// ---------------- final: out = log_softmax(agg2 @ W2 + b2) ----------------

__global__ __launch_bounds__(256) void final_kernel(const float* __restrict__ agg2,
                                                    const float* __restrict__ W2,
                                                    const float* __restrict__ b2,
                                                    float* __restrict__ out, int N) {
    __shared__ float W2t[CDIM * HDIM];  // [j][k]
    __shared__ float b2s[CDIM];
    for (int t = threadIdx.x; t < CDIM * HDIM; t += 256) {
        int j = t / HDIM, k = t % HDIM;
        W2t[t] = W2[k * CDIM + j];
    }
    for (int t = threadIdx.x; t < CDIM; t += 256) b2s[t] = b2[t];
    __syncthreads();

    int n = blockIdx.x * 256 + threadIdx.x;
    if (n >= N) return;

    float a[HDIM];
    const float4* a4 = reinterpret_cast<const float4*>(agg2 + (size_t)n * HDIM);
#pragma unroll
    for (int c = 0; c < HDIM / 4; ++c) {
        float4 v = a4[c];
        a[4 * c + 0] = v.x; a[4 * c + 1] = v.y;
        a[4 * c + 2] = v.z; a[4 * c + 3] = v.w;
    }
    float o[CDIM];
#pragma unroll
    for (int j = 0; j < CDIM; ++j) {
        const float4* w4 = reinterpret_cast<const float4*>(W2t + j * HDIM);
        float s = b2s[j];
#pragma unroll
        for (int c = 0; c < HDIM / 4; ++c) {
            float4 w = w4[c];
            s += a[4 * c + 0] * w.x + a[4 * c + 1] * w.y +
                 a[4 * c + 2] * w.z + a[4 * c + 3] * w.w;
        }
        o[j] = s;
    }
    float m = o[0];
#pragma unroll
    for (int j = 1; j < CDIM; ++j) m = fmaxf(m, o[j]);
    float s = 0.f;
#pragma unroll
    for (int j = 0; j < CDIM; ++j) s += __expf(o[j] - m);
    float l = __logf(s);
    float4* out4 = reinterpret_cast<float4*>(out + (size_t)n * CDIM);
#pragma unroll
    for (int c = 0; c < CDIM / 4; ++c)
        out4[c] = make_float4(o[4 * c + 0] - m - l, o[4 * c + 1] - m - l,
                              o[4 * c + 2] - m - l, o[4 * c + 3] - m - l);
}

// ---------------- launch ----------------

extern "C" void kernel_launch(void* const* d_in, const int* in_sizes, int n_in,
                              void* d_out, int out_size, void* d_ws, size_t ws_size,
                              hipStream_t stream) {
    const float* x  = (const float*)d_in[0];
    const int* edge = (const int*)d_in[1];   // [2, E] int32
    const float* W1 = (const float*)d_in[2];
    const float* b1 = (const float*)d_in[3];
    const float* W2 = (const float*)d_in[4];
    const float* b2 = (const float*)d_in[5];
    float* out = (float*)d_out;

    const int N = in_sizes[0] / NDIM;   // 500000
    const int E = in_sizes[1] / 2;      // 8000000
    const int* src = edge;
    const int* dst = edge + E;

    const int tb = 256;
    const int nbN = (N + tb - 1) / tb;          // blocks over N
    const int NB  = (N + BMASK) >> BSHIFT;      // buckets (1954), <= NBMAX
    const int nbE = (E + CHUNK - 1) / CHUNK;    // chunks for passes A/B

    char* ws = (char*)d_ws;
    size_t off = 0;
    int*   deg    = (int*)(ws + off);   off += (size_t)N * 4;
    int*   cursor = (int*)(ws + off);   off += (size_t)N * 4;
    float* dinv   = (float*)(ws + off); off += (size_t)N * 4;
    float* xw1s   = (float*)(ws + off); off += (size_t)N * HDIM * 4;
    float* hs     = (float*)(ws + off); off += (size_t)N * HDIM * 4;
    float* agg2   = (float*)(ws + off); off += (size_t)N * HDIM * 4;
    int*   esrc   = (int*)(ws + off);   off += (size_t)E * 4;
    int*   hist   = (int*)(ws + off);   off += (size_t)PPART * NBMAX * 4;
    int*   gcur   = (int*)(ws + off);   off += (size_t)PPART * NBMAX * 4;
    int*   bcnt   = (int*)(ws + off);   off += (size_t)NBMAX * 4;

    // tmp (bucket-major packed edges, E*4 = 32MB) aliases agg2 (N*HDIM*4 = 32MB);
    // agg2 is only written by gather2, long after binC has consumed tmp.
    unsigned* tmp = (unsigned*)agg2;

    // ---- CSR build via hierarchical counting sort ----
    hipMemsetAsync(hist, 0, (size_t)PPART * NB * 4, stream);
    histA<<<nbE, tb, 0, stream>>>(dst, hist, E, NB);
    bucket_tot<<<(NB + tb - 1) / tb, tb, 0, stream>>>(hist, bcnt, NB);
    scan_k2<<<1, tb, 0, stream>>>(bcnt, NB);                        // bcnt -> B0 (exclusive)
    part_offsets<<<(NB + tb - 1) / tb, tb, 0, stream>>>(hist, bcnt, gcur, NB);
    scatterB<<<nbE, tb, 0, stream>>>(src, dst, gcur, tmp, E, NB);
    binC<<<NB, tb, 0, stream>>>(tmp, bcnt, deg, cursor, esrc, N, E, NB);

    dinv_kernel<<<nbN, tb, 0, stream>>>(deg, dinv, N);

    // dense matmul xw1s = dinv * (x @ W1)
    xw1_kernel<<<(N + 63) / 64, tb, 0, stream>>>(x, W1, dinv, xw1s, N);

    // layer 1: gather-reduce -> hs = dinv * relu(...)
    gather1<<<(N + 63) / 64, tb, 0, stream>>>(esrc, cursor, deg, dinv, xw1s, b1, hs, N);

    // layer 2: gather-reduce -> agg2 = dn * (sum hs + self)
    gather2<<<(N + 63) / 64, tb, 0, stream>>>(esrc, cursor, deg, dinv, hs, agg2, N);

    // fused projection + log_softmax -> out
    final_kernel<<<nbN, tb, 0, stream>>>(agg2, W2, b2, out, N);
}

// Round 3
// 831.721 us; speedup vs baseline: 2.3632x; 1.2348x over previous
//
#include <hip/hip_runtime.h>
#include <hip/hip_bf16.h>

#define NDIM 100
#define HDIM 16
#define CDIM 20

#define BSH2   10                 // 1024 nodes per bucket
#define BMASK2 ((1 << BSH2) - 1)
#define NB2MAX 768                // supports N <= 786432 (3*256 for LDS scan)
#define CH2    16384              // edges per scatter_sort block
#define LBUF_CAP 18432            // binC LDS staging capacity (mean 16384 + ~16 sd)

// ---------------- pass A: bucket histogram -> bcnt[b] ----------------

__global__ __launch_bounds__(256) void histA(const int* __restrict__ dst,
                                             int* __restrict__ bcnt,
                                             int E, int NB2) {
    __shared__ int lh[NB2MAX];
    for (int t = threadIdx.x; t < NB2MAX; t += 256) lh[t] = 0;
    __syncthreads();

    int base = blockIdx.x * 8192;
    int endv = min(base + 8192, E);
    for (int e = base + threadIdx.x; e < endv; e += 256)
        atomicAdd(&lh[dst[e] >> BSH2], 1);
    __syncthreads();

    for (int t = threadIdx.x; t < NB2; t += 256) {
        int v = lh[t];
        if (v) atomicAdd(&bcnt[t], v);
    }
}

// ---- exclusive scan of bcnt in place (nb <= 2048), 1 block; also seeds gcur ----

__global__ __launch_bounds__(256) void scan_k2(int* __restrict__ bsum,
                                               int* __restrict__ gcur, int nb) {
    __shared__ int part[256];
    int t = threadIdx.x;
    int base = t * 8;
    int loc[8];
    int s = 0;
#pragma unroll
    for (int k = 0; k < 8; ++k) {
        int idx = base + k;
        loc[k] = (idx < nb) ? bsum[idx] : 0;
        s += loc[k];
    }
    part[t] = s;
    __syncthreads();
    for (int off = 1; off < 256; off <<= 1) {
        int add = (t >= off) ? part[t - off] : 0;
        __syncthreads();
        part[t] += add;
        __syncthreads();
    }
    int run = (t > 0) ? part[t - 1] : 0;
#pragma unroll
    for (int k = 0; k < 8; ++k) {
        int idx = base + k;
        if (idx < nb) { bsum[idx] = run; gcur[idx] = run; }
        run += loc[k];
    }
}

// ---------------- pass B: block-local counting sort in LDS + full-line copy-out ----
// Each block sorts CH2 edges by coarse bucket in LDS, then writes one contiguous
// run per bucket to tmp. No dependence on workgroup->XCD mapping.

__global__ __launch_bounds__(256) void scatter_sort(const int* __restrict__ src,
                                                    const int* __restrict__ dst,
                                                    int* __restrict__ gcur,
                                                    unsigned* __restrict__ tmp,
                                                    int E, int NB2) {
    __shared__ unsigned lbuf[CH2];
    __shared__ int lcnt[NB2MAX];   // counts, later local cursors (-> ends)
    __shared__ int lst[NB2MAX];    // local exclusive starts
    __shared__ int gb[NB2MAX];     // global run bases
    __shared__ int part[256];
    const int t = threadIdx.x;

    for (int i = t; i < NB2MAX; i += 256) lcnt[i] = 0;
    __syncthreads();

    int base = blockIdx.x * CH2;
    int endv = min(base + CH2, E);
    for (int e = base + t; e < endv; e += 256)
        atomicAdd(&lcnt[dst[e] >> BSH2], 1);
    __syncthreads();

    // scan 768 counts (3 per thread)
    int c0 = lcnt[3 * t], c1 = lcnt[3 * t + 1], c2 = lcnt[3 * t + 2];
    part[t] = c0 + c1 + c2;
    __syncthreads();
    for (int off = 1; off < 256; off <<= 1) {
        int add = (t >= off) ? part[t - off] : 0;
        __syncthreads();
        part[t] += add;
        __syncthreads();
    }
    int ex = (t > 0) ? part[t - 1] : 0;
    lst[3 * t]     = ex;
    lst[3 * t + 1] = ex + c0;
    lst[3 * t + 2] = ex + c0 + c1;

    // allocate one contiguous global run per bucket
    for (int i = t; i < NB2; i += 256)
        gb[i] = atomicAdd(&gcur[i], lcnt[i]);
    __syncthreads();

    // counts -> cursors
    for (int i = t; i < NB2MAX; i += 256) lcnt[i] = lst[i];
    __syncthreads();

    // scatter into LDS, sorted by bucket
    for (int e = base + t; e < endv; e += 256) {
        int d = dst[e];
        int b = d >> BSH2;
        int pos = atomicAdd(&lcnt[b], 1);
        lbuf[pos] = ((unsigned)src[e] << BSH2) | (unsigned)(d & BMASK2);
    }
    __syncthreads();

    // copy-out: one wave per bucket round-robin, contiguous stores
    int wave = t >> 6, lane = t & 63;
    for (int b = wave; b < NB2; b += 4) {
        int s0 = lst[b], g0 = gb[b];
        int len = lcnt[b] - s0;
        for (int k = lane; k < len; k += 64)
            tmp[(size_t)g0 + k] = lbuf[s0 + k];
    }
}

// ---------------- pass C: one block per bucket -> deg, cursor(end), esrc ----------------
// Node-sort the bucket in LDS, then write esrc linearly (full lines).

__global__ __launch_bounds__(256) void binC(const unsigned* __restrict__ tmp,
                                            const int* __restrict__ B0,
                                            int* __restrict__ deg,
                                            int* __restrict__ cursor,
                                            int* __restrict__ esrc,
                                            int N, int E, int NB2) {
    __shared__ int lbuf[LBUF_CAP];
    __shared__ int lh[1024];
    __shared__ int part[256];
    int b = blockIdx.x, t = threadIdx.x;

    for (int i = t; i < 1024; i += 256) lh[i] = 0;
    __syncthreads();

    int lo = B0[b];
    int hi = (b + 1 < NB2) ? B0[b + 1] : E;

    // per-node histogram (= in-degree)
    for (int i = lo + t; i < hi; i += 256)
        atomicAdd(&lh[tmp[i] & BMASK2], 1);
    __syncthreads();

    int c[4];
    int s = 0;
#pragma unroll
    for (int k = 0; k < 4; ++k) { c[k] = lh[4 * t + k]; s += c[k]; }
    part[t] = s;
    __syncthreads();
    for (int off = 1; off < 256; off <<= 1) {
        int add = (t >= off) ? part[t - off] : 0;
        __syncthreads();
        part[t] += add;
        __syncthreads();
    }
    int run = (t > 0) ? part[t - 1] : 0;  // local exclusive prefix
    bool fits = (hi - lo) <= LBUF_CAP;

#pragma unroll
    for (int k = 0; k < 4; ++k) {
        int node = (b << BSH2) + 4 * t + k;
        int st = run;
        run += c[k];
        if (node < N) {
            deg[node]    = c[k];
            cursor[node] = lo + run;   // global segment end
        }
        lh[4 * t + k] = st;            // local cursor for sweep 2
    }
    __syncthreads();

    if (fits) {
        for (int i = lo + t; i < hi; i += 256) {
            unsigned v = tmp[i];
            int pos = atomicAdd(&lh[v & BMASK2], 1);
            lbuf[pos] = (int)(v >> BSH2);
        }
        __syncthreads();
        for (int i = lo + t; i < hi; i += 256)
            esrc[i] = lbuf[i - lo];
    } else {
        // fallback for pathological bucket sizes
        for (int i = lo + t; i < hi; i += 256) {
            unsigned v = tmp[i];
            int pos = atomicAdd(&lh[v & BMASK2], 1);
            esrc[(size_t)lo + pos] = (int)(v >> BSH2);
        }
    }
}

// ---------------- dinv ----------------

__global__ __launch_bounds__(256) void dinv_kernel(const int* __restrict__ deg,
                                                   float* __restrict__ dinv, int N) {
    int i = blockIdx.x * blockDim.x + threadIdx.x;
    if (i < N) dinv[i] = rsqrtf((float)(deg[i] + 1));  // +1 = self-loop
}

// ---------------- xw1s = dinv[n] * (x @ W1)  ([N,100] @ [100,16], pre-scaled) ----------------

__global__ __launch_bounds__(256) void xw1_kernel(const float* __restrict__ x,
                                                  const float* __restrict__ W1,
                                                  const float* __restrict__ dinv,
                                                  float* __restrict__ xw1s, int N) {
    __shared__ float Ws[NDIM * HDIM];  // [k][j]
    for (int t = threadIdx.x; t < NDIM * HDIM; t += 256) Ws[t] = W1[t];
    __syncthreads();

    const int ln = threadIdx.x >> 2;
    const int q  = threadIdx.x & 3;
    const int node = blockIdx.x * 64 + ln;
    if (node >= N) return;

    const float4* xr  = reinterpret_cast<const float4*>(x + (size_t)node * NDIM);
    const float4* Ws4 = reinterpret_cast<const float4*>(Ws);

    float4 acc = make_float4(0.f, 0.f, 0.f, 0.f);
#pragma unroll
    for (int kk = 0; kk < NDIM / 4; ++kk) {
        float4 xv = xr[kk];
        float xs[4] = {xv.x, xv.y, xv.z, xv.w};
#pragma unroll
        for (int c = 0; c < 4; ++c) {
            float4 w = Ws4[(kk * 4 + c) * 4 + q];
            acc.x += xs[c] * w.x;
            acc.y += xs[c] * w.y;
            acc.z += xs[c] * w.z;
            acc.w += xs[c] * w.w;
        }
    }
    float dn = dinv[node];
    acc.x *= dn; acc.y *= dn; acc.z *= dn; acc.w *= dn;
    reinterpret_cast<float4*>(xw1s + (size_t)node * HDIM)[q] = acc;
}

// ---------------- layer-1 gather: hs = dinv * relu(dn*(sum xw1s[s] + xw1s[n]) + b1) ----

__global__ __launch_bounds__(256) void gather1(const int* __restrict__ esrc,
                                               const int* __restrict__ cursor,
                                               const int* __restrict__ deg,
                                               const float* __restrict__ dinv,
                                               const float* __restrict__ xw1s,
                                               const float* __restrict__ b1,
                                               float* __restrict__ hs, int N) {
    int g  = threadIdx.x >> 2;
    int f4 = threadIdx.x & 3;
    int n  = blockIdx.x * 64 + g;
    if (n >= N) return;

    int end   = cursor[n];
    int start = end - deg[n];
    float dn  = dinv[n];

    const float4* T = reinterpret_cast<const float4*>(xw1s);
    float4 a0 = T[(size_t)n * 4 + f4];  // self term (already dinv-scaled)
    float4 a1 = make_float4(0.f, 0.f, 0.f, 0.f);

    int j = start;
    for (; j + 3 < end; j += 4) {
        int s0 = esrc[j + 0], s1 = esrc[j + 1];
        int s2 = esrc[j + 2], s3 = esrc[j + 3];
        float4 v0 = T[(size_t)s0 * 4 + f4];
        float4 v1 = T[(size_t)s1 * 4 + f4];
        float4 v2 = T[(size_t)s2 * 4 + f4];
        float4 v3 = T[(size_t)s3 * 4 + f4];
        a0.x += v0.x; a0.y += v0.y; a0.z += v0.z; a0.w += v0.w;
        a1.x += v1.x; a1.y += v1.y; a1.z += v1.z; a1.w += v1.w;
        a0.x += v2.x; a0.y += v2.y; a0.z += v2.z; a0.w += v2.w;
        a1.x += v3.x; a1.y += v3.y; a1.z += v3.z; a1.w += v3.w;
    }
    for (; j < end; ++j) {
        int s = esrc[j];
        float4 v = T[(size_t)s * 4 + f4];
        a0.x += v.x; a0.y += v.y; a0.z += v.z; a0.w += v.w;
    }
    float4 acc = make_float4(a0.x + a1.x, a0.y + a1.y, a0.z + a1.z, a0.w + a1.w);
    float4 bv = reinterpret_cast<const float4*>(b1)[f4];
    float4 hv;
    hv.x = dn * fmaxf(dn * acc.x + bv.x, 0.f);
    hv.y = dn * fmaxf(dn * acc.y + bv.y, 0.f);
    hv.z = dn * fmaxf(dn * acc.z + bv.z, 0.f);
    hv.w = dn * fmaxf(dn * acc.w + bv.w, 0.f);
    reinterpret_cast<float4*>(hs)[(size_t)n * 4 + f4] = hv;
}

// ---------------- layer-2 gather: agg2 = dn * (sum hs[s] + hs[n]) ----------------

__global__ __launch_bounds__(256) void gather2(const int* __restrict__ esrc,
                                               const int* __restrict__ cursor,
                                               const int* __restrict__ deg,
                                               const float* __restrict__ dinv,
                                               const float* __restrict__ hs,
                                               float* __restrict__ agg2, int N) {
    int g  = threadIdx.x >> 2;
    int f4 = threadIdx.x & 3;
    int n  = blockIdx.x * 64 + g;
    if (n >= N) return;

    int end   = cursor[n];
    int start = end - deg[n];
    float dn  = dinv[n];

    const float4* T = reinterpret_cast<const float4*>(hs);
    float4 a0 = T[(size_t)n * 4 + f4];  // self term
    float4 a1 = make_float4(0.f, 0.f, 0.f, 0.f);

    int j = start;
    for (; j + 3 < end; j += 4) {
        int s0 = esrc[j + 0], s1 = esrc[j + 1];
        int s2 = esrc[j + 2], s3 = esrc[j + 3];
        float4 v0 = T[(size_t)s0 * 4 + f4];
        float4 v1 = T[(size_t)s1 * 4 + f4];
        float4 v2 = T[(size_t)s2 * 4 + f4];
        float4 v3 = T[(size_t)s3 * 4 + f4];
        a0.x += v0.x; a0.y += v0.y; a0.z += v0.z; a0.w += v0.w;
        a1.x += v1.x; a1.y += v1.y; a1.z += v1.z; a1.w += v1.w;
        a0.x += v2.x; a0.y += v2.y; a0.z += v2.z; a0.w += v2.w;
        a1.x += v3.x; a1.y += v3.y; a1.z += v3.z; a1.w += v3.w;
    }
    for (; j < end; ++j) {
        int s = esrc[j];
        float4 v = T[(size_t)s * 4 + f4];
        a0.x += v.x; a0.y += v.y; a0.z += v.z; a0.w += v.w;
    }
    float4 o;
    o.x = dn * (a0.x + a1.x);
    o.y = dn * (a0.y + a1.y);
    o.z = dn * (a0.z + a1.z);
    o.w = dn * (a0.w + a1.w);
    reinterpret_cast<float4*>(agg2)[(size_t)n * 4 + f4] = o;
}

// ---------------- final: out = log_softmax(agg2 @ W2 + b2) ----------------

__global__ __launch_bounds__(256) void final_kernel(const float* __restrict__ agg2,
                                                    const float* __restrict__ W2,
                                                    const float* __restrict__ b2,
                                                    float* __restrict__ out, int N) {
    __shared__ float W2t[CDIM * HDIM];  // [j][k]
    __shared__ float b2s[CDIM];
    for (int t = threadIdx.x; t < CDIM * HDIM; t += 256) {
        int j = t / HDIM, k = t % HDIM;
        W2t[t] = W2[k * CDIM + j];
    }
    for (int t = threadIdx.x; t < CDIM; t += 256) b2s[t] = b2[t];
    __syncthreads();

    int n = blockIdx.x * 256 + threadIdx.x;
    if (n >= N) return;

    float a[HDIM];
    const float4* a4 = reinterpret_cast<const float4*>(agg2 + (size_t)n * HDIM);
#pragma unroll
    for (int c = 0; c < HDIM / 4; ++c) {
        float4 v = a4[c];
        a[4 * c + 0] = v.x; a[4 * c + 1] = v.y;
        a[4 * c + 2] = v.z; a[4 * c + 3] = v.w;
    }
    float o[CDIM];
#pragma unroll
    for (int j = 0; j < CDIM; ++j) {
        const float4* w4 = reinterpret_cast<const float4*>(W2t + j * HDIM);
        float s = b2s[j];
#pragma unroll
        for (int c = 0; c < HDIM / 4; ++c) {
            float4 w = w4[c];
            s += a[4 * c + 0] * w.x + a[4 * c + 1] * w.y +
                 a[4 * c + 2] * w.z + a[4 * c + 3] * w.w;
        }
        o[j] = s;
    }
    float m = o[0];
#pragma unroll
    for (int j = 1; j < CDIM; ++j) m = fmaxf(m, o[j]);
    float s = 0.f;
#pragma unroll
    for (int j = 0; j < CDIM; ++j) s += __expf(o[j] - m);
    float l = __logf(s);
    float4* out4 = reinterpret_cast<float4*>(out + (size_t)n * CDIM);
#pragma unroll
    for (int c = 0; c < CDIM / 4; ++c)
        out4[c] = make_float4(o[4 * c + 0] - m - l, o[4 * c + 1] - m - l,
                              o[4 * c + 2] - m - l, o[4 * c + 3] - m - l);
}

// ---------------- launch ----------------

extern "C" void kernel_launch(void* const* d_in, const int* in_sizes, int n_in,
                              void* d_out, int out_size, void* d_ws, size_t ws_size,
                              hipStream_t stream) {
    const float* x  = (const float*)d_in[0];
    const int* edge = (const int*)d_in[1];   // [2, E] int32
    const float* W1 = (const float*)d_in[2];
    const float* b1 = (const float*)d_in[3];
    const float* W2 = (const float*)d_in[4];
    const float* b2 = (const float*)d_in[5];
    float* out = (float*)d_out;

    const int N = in_sizes[0] / NDIM;   // 500000
    const int E = in_sizes[1] / 2;      // 8000000
    const int* src = edge;
    const int* dst = edge + E;

    const int tb = 256;
    const int nbN = (N + tb - 1) / tb;
    const int NB2 = (N + BMASK2) >> BSH2;       // 489 coarse buckets

    char* ws = (char*)d_ws;
    size_t off = 0;
    int*   deg    = (int*)(ws + off);   off += (size_t)N * 4;
    int*   cursor = (int*)(ws + off);   off += (size_t)N * 4;
    float* dinv   = (float*)(ws + off); off += (size_t)N * 4;
    float* xw1s   = (float*)(ws + off); off += (size_t)N * HDIM * 4;
    float* hs     = (float*)(ws + off); off += (size_t)N * HDIM * 4;
    float* agg2   = (float*)(ws + off); off += (size_t)N * HDIM * 4;
    int*   esrc   = (int*)(ws + off);   off += (size_t)E * 4;
    int*   bcnt   = (int*)(ws + off);   off += (size_t)NB2MAX * 4;
    int*   gcur   = (int*)(ws + off);   off += (size_t)NB2MAX * 4;

    // tmp (bucket-major packed edges, E*4 = 32MB) aliases agg2 (N*HDIM*4 = 32MB);
    // agg2 is only written by gather2, long after binC has consumed tmp.
    unsigned* tmp = (unsigned*)agg2;

    // ---- CSR build ----
    hipMemsetAsync(bcnt, 0, (size_t)NB2 * 4, stream);
    histA<<<(E + 8191) / 8192, tb, 0, stream>>>(dst, bcnt, E, NB2);
    scan_k2<<<1, tb, 0, stream>>>(bcnt, gcur, NB2);   // bcnt -> B0, seeds gcur
    scatter_sort<<<(E + CH2 - 1) / CH2, tb, 0, stream>>>(src, dst, gcur, tmp, E, NB2);
    binC<<<NB2, tb, 0, stream>>>(tmp, bcnt, deg, cursor, esrc, N, E, NB2);

    dinv_kernel<<<nbN, tb, 0, stream>>>(deg, dinv, N);

    // dense matmul xw1s = dinv * (x @ W1)
    xw1_kernel<<<(N + 63) / 64, tb, 0, stream>>>(x, W1, dinv, xw1s, N);

    // layer 1: gather-reduce -> hs = dinv * relu(...)
    gather1<<<(N + 63) / 64, tb, 0, stream>>>(esrc, cursor, deg, dinv, xw1s, b1, hs, N);

    // layer 2: gather-reduce -> agg2 = dn * (sum hs + self)
    gather2<<<(N + 63) / 64, tb, 0, stream>>>(esrc, cursor, deg, dinv, hs, agg2, N);

    // fused projection + log_softmax -> out
    final_kernel<<<nbN, tb, 0, stream>>>(agg2, W2, b2, out, N);
}

// Round 4
// 785.699 us; speedup vs baseline: 2.5016x; 1.0586x over previous
//
#include <hip/hip_runtime.h>
#include <hip/hip_bf16.h>
#include <hip/hip_fp16.h>

#define NDIM 100
#define HDIM 16
#define CDIM 20

#define BSH2   10                 // 1024 nodes per bucket
#define BMASK2 ((1 << BSH2) - 1)
#define NB2MAX 768                // supports N <= 786432 (3*256 for LDS scan)
#define CH2    16384              // edges per scatter_sort block
#define LBUF_CAP 18432            // binC LDS staging capacity

// fp16 pack/unpack helpers (tables stored fp16, accumulation fp32)
__device__ inline float2 h2f2(unsigned u) {
    __half2 h = *reinterpret_cast<__half2*>(&u);
    return __half22float2(h);
}
__device__ inline unsigned f2h2(float a, float b) {
    __half2 h = __floats2half2_rn(a, b);
    return *reinterpret_cast<unsigned*>(&h);
}

// ---------------- pass A: bucket histogram -> bcnt[b] ----------------

__global__ __launch_bounds__(256) void histA(const int* __restrict__ dst,
                                             int* __restrict__ bcnt,
                                             int E, int NB2) {
    __shared__ int lh[NB2MAX];
    for (int t = threadIdx.x; t < NB2MAX; t += 256) lh[t] = 0;
    __syncthreads();

    int base = blockIdx.x * 8192;
    int endv = min(base + 8192, E);
    for (int e = base + threadIdx.x; e < endv; e += 256)
        atomicAdd(&lh[dst[e] >> BSH2], 1);
    __syncthreads();

    for (int t = threadIdx.x; t < NB2; t += 256) {
        int v = lh[t];
        if (v) atomicAdd(&bcnt[t], v);
    }
}

// ---- exclusive scan of bcnt in place (nb <= 2048), 1 block; also seeds gcur ----

__global__ __launch_bounds__(256) void scan_k2(int* __restrict__ bsum,
                                               int* __restrict__ gcur, int nb) {
    __shared__ int part[256];
    int t = threadIdx.x;
    int base = t * 8;
    int loc[8];
    int s = 0;
#pragma unroll
    for (int k = 0; k < 8; ++k) {
        int idx = base + k;
        loc[k] = (idx < nb) ? bsum[idx] : 0;
        s += loc[k];
    }
    part[t] = s;
    __syncthreads();
    for (int off = 1; off < 256; off <<= 1) {
        int add = (t >= off) ? part[t - off] : 0;
        __syncthreads();
        part[t] += add;
        __syncthreads();
    }
    int run = (t > 0) ? part[t - 1] : 0;
#pragma unroll
    for (int k = 0; k < 8; ++k) {
        int idx = base + k;
        if (idx < nb) { bsum[idx] = run; gcur[idx] = run; }
        run += loc[k];
    }
}

// ---------------- pass B: block-local counting sort in LDS + full-line copy-out ----

__global__ __launch_bounds__(256) void scatter_sort(const int* __restrict__ src,
                                                    const int* __restrict__ dst,
                                                    int* __restrict__ gcur,
                                                    unsigned* __restrict__ tmp,
                                                    int E, int NB2) {
    __shared__ unsigned lbuf[CH2];
    __shared__ int lcnt[NB2MAX];   // counts, later local cursors (-> ends)
    __shared__ int lst[NB2MAX];    // local exclusive starts
    __shared__ int gb[NB2MAX];     // global run bases
    __shared__ int part[256];
    const int t = threadIdx.x;

    for (int i = t; i < NB2MAX; i += 256) lcnt[i] = 0;
    __syncthreads();

    int base = blockIdx.x * CH2;
    int endv = min(base + CH2, E);
    for (int e = base + t; e < endv; e += 256)
        atomicAdd(&lcnt[dst[e] >> BSH2], 1);
    __syncthreads();

    int c0 = lcnt[3 * t], c1 = lcnt[3 * t + 1], c2 = lcnt[3 * t + 2];
    part[t] = c0 + c1 + c2;
    __syncthreads();
    for (int off = 1; off < 256; off <<= 1) {
        int add = (t >= off) ? part[t - off] : 0;
        __syncthreads();
        part[t] += add;
        __syncthreads();
    }
    int ex = (t > 0) ? part[t - 1] : 0;
    lst[3 * t]     = ex;
    lst[3 * t + 1] = ex + c0;
    lst[3 * t + 2] = ex + c0 + c1;

    for (int i = t; i < NB2; i += 256)
        gb[i] = atomicAdd(&gcur[i], lcnt[i]);
    __syncthreads();

    for (int i = t; i < NB2MAX; i += 256) lcnt[i] = lst[i];
    __syncthreads();

    for (int e = base + t; e < endv; e += 256) {
        int d = dst[e];
        int b = d >> BSH2;
        int pos = atomicAdd(&lcnt[b], 1);
        lbuf[pos] = ((unsigned)src[e] << BSH2) | (unsigned)(d & BMASK2);
    }
    __syncthreads();

    int wave = t >> 6, lane = t & 63;
    for (int b = wave; b < NB2; b += 4) {
        int s0 = lst[b], g0 = gb[b];
        int len = lcnt[b] - s0;
        for (int k = lane; k < len; k += 64)
            tmp[(size_t)g0 + k] = lbuf[s0 + k];
    }
}

// ---------------- pass C: one block per bucket -> deg, cursor(end), esrc ----------------

__global__ __launch_bounds__(256) void binC(const unsigned* __restrict__ tmp,
                                            const int* __restrict__ B0,
                                            int* __restrict__ deg,
                                            int* __restrict__ cursor,
                                            int* __restrict__ esrc,
                                            int N, int E, int NB2) {
    __shared__ int lbuf[LBUF_CAP];
    __shared__ int lh[1024];
    __shared__ int part[256];
    int b = blockIdx.x, t = threadIdx.x;

    for (int i = t; i < 1024; i += 256) lh[i] = 0;
    __syncthreads();

    int lo = B0[b];
    int hi = (b + 1 < NB2) ? B0[b + 1] : E;

    for (int i = lo + t; i < hi; i += 256)
        atomicAdd(&lh[tmp[i] & BMASK2], 1);
    __syncthreads();

    int c[4];
    int s = 0;
#pragma unroll
    for (int k = 0; k < 4; ++k) { c[k] = lh[4 * t + k]; s += c[k]; }
    part[t] = s;
    __syncthreads();
    for (int off = 1; off < 256; off <<= 1) {
        int add = (t >= off) ? part[t - off] : 0;
        __syncthreads();
        part[t] += add;
        __syncthreads();
    }
    int run = (t > 0) ? part[t - 1] : 0;
    bool fits = (hi - lo) <= LBUF_CAP;

#pragma unroll
    for (int k = 0; k < 4; ++k) {
        int node = (b << BSH2) + 4 * t + k;
        int st = run;
        run += c[k];
        if (node < N) {
            deg[node]    = c[k];
            cursor[node] = lo + run;
        }
        lh[4 * t + k] = st;
    }
    __syncthreads();

    if (fits) {
        for (int i = lo + t; i < hi; i += 256) {
            unsigned v = tmp[i];
            int pos = atomicAdd(&lh[v & BMASK2], 1);
            lbuf[pos] = (int)(v >> BSH2);
        }
        __syncthreads();
        for (int i = lo + t; i < hi; i += 256)
            esrc[i] = lbuf[i - lo];
    } else {
        for (int i = lo + t; i < hi; i += 256) {
            unsigned v = tmp[i];
            int pos = atomicAdd(&lh[v & BMASK2], 1);
            esrc[(size_t)lo + pos] = (int)(v >> BSH2);
        }
    }
}

// ---------------- dinv ----------------

__global__ __launch_bounds__(256) void dinv_kernel(const int* __restrict__ deg,
                                                   float* __restrict__ dinv, int N) {
    int i = blockIdx.x * blockDim.x + threadIdx.x;
    if (i < N) dinv[i] = rsqrtf((float)(deg[i] + 1));  // +1 = self-loop
}

// ---------------- xw1h = fp16( dinv[n] * (x @ W1) )  ([N,100] @ [100,16]) ----------------

__global__ __launch_bounds__(256) void xw1_kernel(const float* __restrict__ x,
                                                  const float* __restrict__ W1,
                                                  const float* __restrict__ dinv,
                                                  __half* __restrict__ xw1h, int N) {
    __shared__ float Ws[NDIM * HDIM];  // [k][j]
    for (int t = threadIdx.x; t < NDIM * HDIM; t += 256) Ws[t] = W1[t];
    __syncthreads();

    const int ln = threadIdx.x >> 2;
    const int q  = threadIdx.x & 3;
    const int node = blockIdx.x * 64 + ln;
    if (node >= N) return;

    const float4* xr  = reinterpret_cast<const float4*>(x + (size_t)node * NDIM);
    const float4* Ws4 = reinterpret_cast<const float4*>(Ws);

    float4 acc = make_float4(0.f, 0.f, 0.f, 0.f);
#pragma unroll
    for (int kk = 0; kk < NDIM / 4; ++kk) {
        float4 xv = xr[kk];
        float xs[4] = {xv.x, xv.y, xv.z, xv.w};
#pragma unroll
        for (int c = 0; c < 4; ++c) {
            float4 w = Ws4[(kk * 4 + c) * 4 + q];
            acc.x += xs[c] * w.x;
            acc.y += xs[c] * w.y;
            acc.z += xs[c] * w.z;
            acc.w += xs[c] * w.w;
        }
    }
    float dn = dinv[node];
    uint2 o;
    o.x = f2h2(dn * acc.x, dn * acc.y);
    o.y = f2h2(dn * acc.z, dn * acc.w);
    reinterpret_cast<uint2*>(xw1h)[(size_t)node * 4 + q] = o;
}

// ---------------- layer-1 gather: hsh = fp16(dinv * relu(dn*(sum + self) + b1)) ----
// 4 lanes per node, 8B (half4) per lane; 64 nodes per 256-thread block.

__global__ __launch_bounds__(256) void gather1(const int* __restrict__ esrc,
                                               const int* __restrict__ cursor,
                                               const int* __restrict__ deg,
                                               const float* __restrict__ dinv,
                                               const __half* __restrict__ xw1h,
                                               const float* __restrict__ b1,
                                               __half* __restrict__ hsh, int N) {
    int g  = threadIdx.x >> 2;
    int f4 = threadIdx.x & 3;
    int n  = blockIdx.x * 64 + g;
    if (n >= N) return;

    int end   = cursor[n];
    int start = end - deg[n];
    float dn  = dinv[n];

    const uint2* T = reinterpret_cast<const uint2*>(xw1h);
    uint2 sv = T[(size_t)n * 4 + f4];
    float2 s01 = h2f2(sv.x), s23 = h2f2(sv.y);
    float4 a0 = make_float4(s01.x, s01.y, s23.x, s23.y);  // self term
    float4 a1 = make_float4(0.f, 0.f, 0.f, 0.f);

    int j = start;
    for (; j + 3 < end; j += 4) {
        int i0 = esrc[j + 0], i1 = esrc[j + 1];
        int i2 = esrc[j + 2], i3 = esrc[j + 3];
        uint2 v0 = T[(size_t)i0 * 4 + f4];
        uint2 v1 = T[(size_t)i1 * 4 + f4];
        uint2 v2 = T[(size_t)i2 * 4 + f4];
        uint2 v3 = T[(size_t)i3 * 4 + f4];
        float2 p, q;
        p = h2f2(v0.x); q = h2f2(v0.y);
        a0.x += p.x; a0.y += p.y; a0.z += q.x; a0.w += q.y;
        p = h2f2(v1.x); q = h2f2(v1.y);
        a1.x += p.x; a1.y += p.y; a1.z += q.x; a1.w += q.y;
        p = h2f2(v2.x); q = h2f2(v2.y);
        a0.x += p.x; a0.y += p.y; a0.z += q.x; a0.w += q.y;
        p = h2f2(v3.x); q = h2f2(v3.y);
        a1.x += p.x; a1.y += p.y; a1.z += q.x; a1.w += q.y;
    }
    for (; j < end; ++j) {
        int s = esrc[j];
        uint2 v = T[(size_t)s * 4 + f4];
        float2 p = h2f2(v.x), q = h2f2(v.y);
        a0.x += p.x; a0.y += p.y; a0.z += q.x; a0.w += q.y;
    }
    float4 acc = make_float4(a0.x + a1.x, a0.y + a1.y, a0.z + a1.z, a0.w + a1.w);
    float4 bv = reinterpret_cast<const float4*>(b1)[f4];
    float hx = dn * fmaxf(dn * acc.x + bv.x, 0.f);
    float hy = dn * fmaxf(dn * acc.y + bv.y, 0.f);
    float hz = dn * fmaxf(dn * acc.z + bv.z, 0.f);
    float hw = dn * fmaxf(dn * acc.w + bv.w, 0.f);
    uint2 o;
    o.x = f2h2(hx, hy);
    o.y = f2h2(hz, hw);
    reinterpret_cast<uint2*>(hsh)[(size_t)n * 4 + f4] = o;
}

// ---------------- layer-2 gather: agg2 = dn * (sum hsh[s] + hsh[n]) (fp32 out) ----

__global__ __launch_bounds__(256) void gather2(const int* __restrict__ esrc,
                                               const int* __restrict__ cursor,
                                               const int* __restrict__ deg,
                                               const float* __restrict__ dinv,
                                               const __half* __restrict__ hsh,
                                               float* __restrict__ agg2, int N) {
    int g  = threadIdx.x >> 2;
    int f4 = threadIdx.x & 3;
    int n  = blockIdx.x * 64 + g;
    if (n >= N) return;

    int end   = cursor[n];
    int start = end - deg[n];
    float dn  = dinv[n];

    const uint2* T = reinterpret_cast<const uint2*>(hsh);
    uint2 sv = T[(size_t)n * 4 + f4];
    float2 s01 = h2f2(sv.x), s23 = h2f2(sv.y);
    float4 a0 = make_float4(s01.x, s01.y, s23.x, s23.y);  // self term
    float4 a1 = make_float4(0.f, 0.f, 0.f, 0.f);

    int j = start;
    for (; j + 3 < end; j += 4) {
        int i0 = esrc[j + 0], i1 = esrc[j + 1];
        int i2 = esrc[j + 2], i3 = esrc[j + 3];
        uint2 v0 = T[(size_t)i0 * 4 + f4];
        uint2 v1 = T[(size_t)i1 * 4 + f4];
        uint2 v2 = T[(size_t)i2 * 4 + f4];
        uint2 v3 = T[(size_t)i3 * 4 + f4];
        float2 p, q;
        p = h2f2(v0.x); q = h2f2(v0.y);
        a0.x += p.x; a0.y += p.y; a0.z += q.x; a0.w += q.y;
        p = h2f2(v1.x); q = h2f2(v1.y);
        a1.x += p.x; a1.y += p.y; a1.z += q.x; a1.w += q.y;
        p = h2f2(v2.x); q = h2f2(v2.y);
        a0.x += p.x; a0.y += p.y; a0.z += q.x; a0.w += q.y;
        p = h2f2(v3.x); q = h2f2(v3.y);
        a1.x += p.x; a1.y += p.y; a1.z += q.x; a1.w += q.y;
    }
    for (; j < end; ++j) {
        int s = esrc[j];
        uint2 v = T[(size_t)s * 4 + f4];
        float2 p = h2f2(v.x), q = h2f2(v.y);
        a0.x += p.x; a0.y += p.y; a0.z += q.x; a0.w += q.y;
    }
    float4 o;
    o.x = dn * (a0.x + a1.x);
    o.y = dn * (a0.y + a1.y);
    o.z = dn * (a0.z + a1.z);
    o.w = dn * (a0.w + a1.w);
    reinterpret_cast<float4*>(agg2)[(size_t)n * 4 + f4] = o;
}

// ---------------- final: out = log_softmax(agg2 @ W2 + b2) ----------------

__global__ __launch_bounds__(256) void final_kernel(const float* __restrict__ agg2,
                                                    const float* __restrict__ W2,
                                                    const float* __restrict__ b2,
                                                    float* __restrict__ out, int N) {
    __shared__ float W2t[CDIM * HDIM];  // [j][k]
    __shared__ float b2s[CDIM];
    for (int t = threadIdx.x; t < CDIM * HDIM; t += 256) {
        int j = t / HDIM, k = t % HDIM;
        W2t[t] = W2[k * CDIM + j];
    }
    for (int t = threadIdx.x; t < CDIM; t += 256) b2s[t] = b2[t];
    __syncthreads();

    int n = blockIdx.x * 256 + threadIdx.x;
    if (n >= N) return;

    float a[HDIM];
    const float4* a4 = reinterpret_cast<const float4*>(agg2 + (size_t)n * HDIM);
#pragma unroll
    for (int c = 0; c < HDIM / 4; ++c) {
        float4 v = a4[c];
        a[4 * c + 0] = v.x; a[4 * c + 1] = v.y;
        a[4 * c + 2] = v.z; a[4 * c + 3] = v.w;
    }
    float o[CDIM];
#pragma unroll
    for (int j = 0; j < CDIM; ++j) {
        const float4* w4 = reinterpret_cast<const float4*>(W2t + j * HDIM);
        float s = b2s[j];
#pragma unroll
        for (int c = 0; c < HDIM / 4; ++c) {
            float4 w = w4[c];
            s += a[4 * c + 0] * w.x + a[4 * c + 1] * w.y +
                 a[4 * c + 2] * w.z + a[4 * c + 3] * w.w;
        }
        o[j] = s;
    }
    float m = o[0];
#pragma unroll
    for (int j = 1; j < CDIM; ++j) m = fmaxf(m, o[j]);
    float s = 0.f;
#pragma unroll
    for (int j = 0; j < CDIM; ++j) s += __expf(o[j] - m);
    float l = __logf(s);
    float4* out4 = reinterpret_cast<float4*>(out + (size_t)n * CDIM);
#pragma unroll
    for (int c = 0; c < CDIM / 4; ++c)
        out4[c] = make_float4(o[4 * c + 0] - m - l, o[4 * c + 1] - m - l,
                              o[4 * c + 2] - m - l, o[4 * c + 3] - m - l);
}

// ---------------- launch ----------------

extern "C" void kernel_launch(void* const* d_in, const int* in_sizes, int n_in,
                              void* d_out, int out_size, void* d_ws, size_t ws_size,
                              hipStream_t stream) {
    const float* x  = (const float*)d_in[0];
    const int* edge = (const int*)d_in[1];   // [2, E] int32
    const float* W1 = (const float*)d_in[2];
    const float* b1 = (const float*)d_in[3];
    const float* W2 = (const float*)d_in[4];
    const float* b2 = (const float*)d_in[5];
    float* out = (float*)d_out;

    const int N = in_sizes[0] / NDIM;   // 500000
    const int E = in_sizes[1] / 2;      // 8000000
    const int* src = edge;
    const int* dst = edge + E;

    const int tb = 256;
    const int nbN = (N + tb - 1) / tb;
    const int NB2 = (N + BMASK2) >> BSH2;       // 489 coarse buckets

    char* ws = (char*)d_ws;
    size_t off = 0;
    int*    deg    = (int*)(ws + off);    off += (size_t)N * 4;
    int*    cursor = (int*)(ws + off);    off += (size_t)N * 4;
    float*  dinv   = (float*)(ws + off);  off += (size_t)N * 4;
    __half* xw1h   = (__half*)(ws + off); off += (size_t)N * HDIM * 2;
    __half* hsh    = (__half*)(ws + off); off += (size_t)N * HDIM * 2;
    float*  agg2   = (float*)(ws + off);  off += (size_t)N * HDIM * 4;
    int*    esrc   = (int*)(ws + off);    off += (size_t)E * 4;
    int*    bcnt   = (int*)(ws + off);    off += (size_t)NB2MAX * 4;
    int*    gcur   = (int*)(ws + off);    off += (size_t)NB2MAX * 4;

    // tmp (bucket-major packed edges, E*4 = 32MB) aliases agg2 (N*HDIM*4 = 32MB);
    // agg2 is only written by gather2, long after binC has consumed tmp.
    unsigned* tmp = (unsigned*)agg2;

    // ---- CSR build ----
    hipMemsetAsync(bcnt, 0, (size_t)NB2 * 4, stream);
    histA<<<(E + 8191) / 8192, tb, 0, stream>>>(dst, bcnt, E, NB2);
    scan_k2<<<1, tb, 0, stream>>>(bcnt, gcur, NB2);   // bcnt -> B0, seeds gcur
    scatter_sort<<<(E + CH2 - 1) / CH2, tb, 0, stream>>>(src, dst, gcur, tmp, E, NB2);
    binC<<<NB2, tb, 0, stream>>>(tmp, bcnt, deg, cursor, esrc, N, E, NB2);

    dinv_kernel<<<nbN, tb, 0, stream>>>(deg, dinv, N);

    // dense matmul xw1h = fp16(dinv * (x @ W1))
    xw1_kernel<<<(N + 63) / 64, tb, 0, stream>>>(x, W1, dinv, xw1h, N);

    // layer 1: gather-reduce -> hsh = fp16(dinv * relu(...))
    gather1<<<(N + 63) / 64, tb, 0, stream>>>(esrc, cursor, deg, dinv, xw1h, b1, hsh, N);

    // layer 2: gather-reduce -> agg2 = dn * (sum hsh + self)
    gather2<<<(N + 63) / 64, tb, 0, stream>>>(esrc, cursor, deg, dinv, hsh, agg2, N);

    // fused projection + log_softmax -> out
    final_kernel<<<nbN, tb, 0, stream>>>(agg2, W2, b2, out, N);
}